// Round 4
// baseline (131.343 us; speedup 1.0000x reference)
//
#include <hip/hip_runtime.h>

#define B_ 8
#define D_ 256
#define N_ 32768
#define F_ 256
#define K_ 16
#define NCH 64        // chunks per batch
#define CHN 512       // n per chunk

__device__ __forceinline__ float sum4(float4 v) { return v.x + v.y + v.z + v.w; }
__device__ __forceinline__ float dot4(float4 a, float4 b) {
  return a.x * b.x + a.y * b.y + a.z * b.z + a.w * b.w;
}

// ---------------------------------------------------------------------------
// Fused kernel: block = (b, chunk of 512 n), 512 threads.
// Phase 1: e[chunk] = exp(-(q . k_n)/16) -> LDS, + chunk scalars (Se, Se2, Se3).
// Phase 2: wave w sweeps f = w*32..w*32+31; per f, lanes dot V[f][chunk] with
//          (1, e, e^2, e^3), shfl-reduce, lane0 stores one float4 partial.
// No e materialization in HBM, no inter-kernel gap, no atomics.
// ---------------------------------------------------------------------------
__global__ __launch_bounds__(512) void fused_kernel(
    const float* __restrict__ q, const float* __restrict__ keys,
    const float* __restrict__ values, float4* __restrict__ partials,
    float4* __restrict__ scal) {
  const int b = blockIdx.x >> 6;
  const int ch = blockIdx.x & 63;
  const int t = threadIdx.x;
  const int c = t & 127;   // float4 n-column within chunk
  const int g = t >> 7;    // d-quarter

  __shared__ float qs[D_];
  __shared__ float4 part[3][128];
  __shared__ float e_lds[CHN];
  __shared__ float pr[8][3];

  if (t < D_) qs[t] = q[b * D_ + t];
  __syncthreads();

  const int n0 = ch * CHN + c * 4;
  const float* kp = keys + (size_t)b * D_ * N_ + (size_t)(g * 64) * N_ + n0;
  const float* qg = qs + g * 64;
  float ax = 0.f, ay = 0.f, az = 0.f, aw = 0.f;
#pragma unroll 8
  for (int d = 0; d < 64; ++d) {
    float4 kv = *reinterpret_cast<const float4*>(kp + (size_t)d * N_);
    float qd = qg[d];
    ax += qd * kv.x; ay += qd * kv.y; az += qd * kv.z; aw += qd * kv.w;
  }
  if (g > 0) part[g - 1][c] = make_float4(ax, ay, az, aw);
  __syncthreads();

  float s1 = 0.f, s2 = 0.f, s3 = 0.f;
  if (g == 0) {
    float4 p1 = part[0][c], p2 = part[1][c], p3 = part[2][c];
    float4 ev;
    ev.x = __expf(-0.0625f * (ax + p1.x + p2.x + p3.x));
    ev.y = __expf(-0.0625f * (ay + p1.y + p2.y + p3.y));
    ev.z = __expf(-0.0625f * (az + p1.z + p2.z + p3.z));
    ev.w = __expf(-0.0625f * (aw + p1.w + p2.w + p3.w));
    *reinterpret_cast<float4*>(e_lds + c * 4) = ev;
    float4 e2 = make_float4(ev.x * ev.x, ev.y * ev.y, ev.z * ev.z, ev.w * ev.w);
    s1 = sum4(ev);
    s2 = sum4(e2);
    s3 = e2.x * ev.x + e2.y * ev.y + e2.z * ev.z + e2.w * ev.w;
  }
#pragma unroll
  for (int off = 32; off > 0; off >>= 1) {
    s1 += __shfl_xor(s1, off, 64);
    s2 += __shfl_xor(s2, off, 64);
    s3 += __shfl_xor(s3, off, 64);
  }
  if ((t & 63) == 0) { pr[t >> 6][0] = s1; pr[t >> 6][1] = s2; pr[t >> 6][2] = s3; }
  __syncthreads();
  if (t == 0) {
    float r1 = 0.f, r2 = 0.f, r3 = 0.f;
#pragma unroll
    for (int w = 0; w < 8; ++w) { r1 += pr[w][0]; r2 += pr[w][1]; r3 += pr[w][2]; }
    scal[b * NCH + ch] = make_float4(r1, r2, r3, 0.f);
  }

  // ---- Phase 2: values sweep ----
  const int w = t >> 6, lane = t & 63;
  // hoist this lane's e slice + powers (2 float4 of e -> 8 float4 total)
  float4 e1a = *reinterpret_cast<const float4*>(e_lds + lane * 4);
  float4 e1b = *reinterpret_cast<const float4*>(e_lds + 256 + lane * 4);
  float4 e2a = make_float4(e1a.x * e1a.x, e1a.y * e1a.y, e1a.z * e1a.z, e1a.w * e1a.w);
  float4 e2b = make_float4(e1b.x * e1b.x, e1b.y * e1b.y, e1b.z * e1b.z, e1b.w * e1b.w);
  float4 e3a = make_float4(e2a.x * e1a.x, e2a.y * e1a.y, e2a.z * e1a.z, e2a.w * e1a.w);
  float4 e3b = make_float4(e2b.x * e1b.x, e2b.y * e1b.y, e2b.z * e1b.z, e2b.w * e1b.w);

  const float* vbase = values + ((size_t)b * F_ + w * 32) * N_ + ch * CHN;
  float4* pout = partials + ((size_t)(b * NCH + ch)) * F_ + w * 32;
#pragma unroll 2
  for (int j = 0; j < 32; ++j) {
    const float* vp = vbase + (size_t)j * N_;
    float4 v0 = *reinterpret_cast<const float4*>(vp + lane * 4);
    float4 v1 = *reinterpret_cast<const float4*>(vp + 256 + lane * 4);
    float m0 = sum4(v0) + sum4(v1);
    float m1 = dot4(v0, e1a) + dot4(v1, e1b);
    float m2 = dot4(v0, e2a) + dot4(v1, e2b);
    float m3 = dot4(v0, e3a) + dot4(v1, e3b);
#pragma unroll
    for (int off = 32; off > 0; off >>= 1) {
      m0 += __shfl_xor(m0, off, 64);
      m1 += __shfl_xor(m1, off, 64);
      m2 += __shfl_xor(m2, off, 64);
      m3 += __shfl_xor(m3, off, 64);
    }
    if (lane == 0) pout[j] = make_float4(m0, m1, m2, m3);
  }
}

// ---------------------------------------------------------------------------
// Reduce kernel: 8 blocks x 256 threads. Thread f sums 64 chunk-partials in
// double, lane-reduced scalars -> analytic epilogue (series in alpha, exact
// to ~1e-13 rel), writes out[b][k][f] for k=0..15.
// ---------------------------------------------------------------------------
__global__ __launch_bounds__(256) void reduce_kernel(
    const float4* __restrict__ partials, const float4* __restrict__ scal,
    float* __restrict__ out) {
  const int b = blockIdx.x;
  const int t = threadIdx.x;  // = f

  double V0 = 0.0, V1 = 0.0, V2 = 0.0, V3 = 0.0;
  const float4* pb = partials + (size_t)b * NCH * F_ + t;
#pragma unroll 4
  for (int c = 0; c < NCH; ++c) {
    float4 p = pb[(size_t)c * F_];
    V0 += (double)p.x; V1 += (double)p.y; V2 += (double)p.z; V3 += (double)p.w;
  }

  __shared__ double sc[3];
  if (t < 64) {
    double z1 = 0.0, w2 = 0.0, w3 = 0.0;
    float4 s = scal[b * NCH + t];
    z1 = (double)s.x; w2 = (double)s.y; w3 = (double)s.z;
#pragma unroll
    for (int off = 32; off > 0; off >>= 1) {
      z1 += __shfl_xor(z1, off, 64);
      w2 += __shfl_xor(w2, off, 64);
      w3 += __shfl_xor(w3, off, 64);
    }
    if (t == 0) { sc[0] = z1; sc[1] = w2; sc[2] = w3; }
  }
  __syncthreads();

  const double z1 = sc[0], w2 = sc[1], w3 = sc[2];
  const double iZ1 = 1.0 / z1;
  const double M2 = w2 * iZ1 * iZ1;
  const double M3 = w3 * iZ1 * iZ1 * iZ1;
  const double Z2 = (double)N_ + 1.0 + 0.5 * M2 + M3 / 6.0;
  const double T2 = (double)N_ + 2.0 + 2.0 * M2 + (4.0 / 3.0) * M3;
  const double iZ2 = 1.0 / Z2;
  const double qd = T2 * iZ2 * iZ2;

  const double W1 = V1 * iZ1;
  const double W2 = V2 * iZ1 * iZ1;
  const double W3 = V3 * iZ1 * iZ1 * iZ1;
  const double A  = (V0 + W1 + 0.5 * W2 + W3 / 6.0) * iZ2;
  const double Bd = (V0 + 2.0 * W1 + 2.0 * W2 + (4.0 / 3.0) * W3) * iZ2 * iZ2;
  const double C  = qd * A - Bd;

  float* ob = out + (size_t)b * K_ * F_ + t;
#pragma unroll
  for (int k = 0; k < K_; ++k) ob[(size_t)k * F_] = (float)(A + (double)k * C);
}

extern "C" void kernel_launch(void* const* d_in, const int* in_sizes, int n_in,
                              void* d_out, int out_size, void* d_ws, size_t ws_size,
                              hipStream_t stream) {
  const float* q = (const float*)d_in[0];
  const float* keys = (const float*)d_in[1];
  const float* values = (const float*)d_in[2];
  float* out = (float*)d_out;
  float4* partials = (float4*)d_ws;                       // 8*64*256 float4 = 2 MB
  float4* scal = partials + (size_t)B_ * NCH * F_;        // 512 float4

  fused_kernel<<<dim3(B_ * NCH), dim3(512), 0, stream>>>(q, keys, values,
                                                         partials, scal);
  reduce_kernel<<<dim3(B_), dim3(256), 0, stream>>>(partials, scal, out);
}

// Round 5
// 126.372 us; speedup vs baseline: 1.0393x; 1.0393x over previous
//
#include <hip/hip_runtime.h>

#define B_ 8
#define D_ 256
#define N_ 32768
#define F_ 256
#define K_ 16
#define NCH 64        // chunks per batch
#define CHN 512       // n per chunk

__device__ __forceinline__ float sum4(float4 v) { return v.x + v.y + v.z + v.w; }
__device__ __forceinline__ float dot4(float4 a, float4 b) {
  return a.x * b.x + a.y * b.y + a.z * b.z + a.w * b.w;
}

// ---------------------------------------------------------------------------
// Fused kernel: block = (b, chunk of 512 n), 512 threads, 2 blocks/CU.
// Phase 1: e[chunk] = exp(-(q . k_n)/16) -> LDS + exact chunk scalars
//          (Se, Se2, Se3).
// Phase 2: wave w owns f = w*32..w*32+31. Lane l owns n-slice {l*4..+3,
//          256+l*4..+3}. Pure load+FMA loop into 64 register accumulators
//          (m0[j] = sum v, m1[j] = sum e*v), NO cross-lane ops.
// Tail:    one merge-butterfly (126 shfls) -> lane L holds total of value L;
//          coalesced stores to m0/m1 planes.
// ---------------------------------------------------------------------------
__global__ __launch_bounds__(512, 4) void fused_kernel(
    const float* __restrict__ q, const float* __restrict__ keys,
    const float* __restrict__ values, float* __restrict__ p0,
    float* __restrict__ p1, float4* __restrict__ scal) {
  const int b = blockIdx.x >> 6;
  const int ch = blockIdx.x & 63;
  const int t = threadIdx.x;
  const int c = t & 127;   // float4 n-column within chunk
  const int g = t >> 7;    // d-quarter

  __shared__ float qs[D_];
  __shared__ float4 part[3][128];
  __shared__ float e_lds[CHN];
  __shared__ float pr[8][3];

  if (t < D_) qs[t] = q[b * D_ + t];
  __syncthreads();

  // ---- Phase 1: keys -> e ----
  const int n0 = ch * CHN + c * 4;
  const float* kp = keys + (size_t)b * D_ * N_ + (size_t)(g * 64) * N_ + n0;
  const float* qg = qs + g * 64;
  float ax = 0.f, ay = 0.f, az = 0.f, aw = 0.f;
#pragma unroll 16
  for (int d = 0; d < 64; ++d) {
    float4 kv = *reinterpret_cast<const float4*>(kp + (size_t)d * N_);
    float qd = qg[d];
    ax += qd * kv.x; ay += qd * kv.y; az += qd * kv.z; aw += qd * kv.w;
  }
  if (g > 0) part[g - 1][c] = make_float4(ax, ay, az, aw);
  __syncthreads();

  float s1 = 0.f, s2 = 0.f, s3 = 0.f;
  if (g == 0) {
    float4 p1v = part[0][c], p2v = part[1][c], p3v = part[2][c];
    float4 ev;
    ev.x = __expf(-0.0625f * (ax + p1v.x + p2v.x + p3v.x));
    ev.y = __expf(-0.0625f * (ay + p1v.y + p2v.y + p3v.y));
    ev.z = __expf(-0.0625f * (az + p1v.z + p2v.z + p3v.z));
    ev.w = __expf(-0.0625f * (aw + p1v.w + p2v.w + p3v.w));
    *reinterpret_cast<float4*>(e_lds + c * 4) = ev;
    float4 e2 = make_float4(ev.x * ev.x, ev.y * ev.y, ev.z * ev.z, ev.w * ev.w);
    s1 = sum4(ev);
    s2 = sum4(e2);
    s3 = e2.x * ev.x + e2.y * ev.y + e2.z * ev.z + e2.w * ev.w;
  }
#pragma unroll
  for (int off = 32; off > 0; off >>= 1) {
    s1 += __shfl_xor(s1, off, 64);
    s2 += __shfl_xor(s2, off, 64);
    s3 += __shfl_xor(s3, off, 64);
  }
  if ((t & 63) == 0) { pr[t >> 6][0] = s1; pr[t >> 6][1] = s2; pr[t >> 6][2] = s3; }
  __syncthreads();
  if (t == 0) {
    float r1 = 0.f, r2 = 0.f, r3 = 0.f;
#pragma unroll
    for (int w = 0; w < 8; ++w) { r1 += pr[w][0]; r2 += pr[w][1]; r3 += pr[w][2]; }
    scal[b * NCH + ch] = make_float4(r1, r2, r3, 0.f);
  }

  // ---- Phase 2: values sweep, register accumulation only ----
  const int w = t >> 6, lane = t & 63;
  const float4 e1a = *reinterpret_cast<const float4*>(e_lds + lane * 4);
  const float4 e1b = *reinterpret_cast<const float4*>(e_lds + 256 + lane * 4);

  // vals[j] = m0 partial for f=w*32+j; vals[32+j] = m1 partial
  float vals[64];
  const float* vbase = values + ((size_t)b * F_ + w * 32) * N_ + ch * CHN + lane * 4;
#pragma unroll
  for (int j = 0; j < 32; ++j) {
    const float* vp = vbase + (size_t)j * N_;
    float4 v0 = *reinterpret_cast<const float4*>(vp);
    float4 v1 = *reinterpret_cast<const float4*>(vp + 256);
    vals[j]      = sum4(v0) + sum4(v1);
    vals[32 + j] = dot4(v0, e1a) + dot4(v1, e1b);
  }

  // merge-butterfly: 6 levels; after level L, half as many values.
  // End state: lane L holds the wave-total of original value index L.
#pragma unroll
  for (int lev = 0; lev < 6; ++lev) {
    const int s = 32 >> lev;
    const int nv = 32 >> lev;
    const bool upper = (lane & s) != 0;
#pragma unroll
    for (int i = 0; i < nv; ++i) {
      float keep = upper ? vals[i + nv] : vals[i];
      float send = upper ? vals[i] : vals[i + nv];
      vals[i] = keep + __shfl_xor(send, s, 64);
    }
  }

  const int fl = lane & 31;
  const size_t pidx = ((size_t)(b * NCH + ch)) * F_ + w * 32 + fl;
  if (lane < 32) p0[pidx] = vals[0];
  else           p1[pidx] = vals[0];
}

// ---------------------------------------------------------------------------
// Reduce kernel: 8 blocks x 256 threads; thread = f. Sum 64 chunk partials in
// double, then analytic epilogue:
//   A = (V0 + V1/Z1)/Z2, B = (V0 + 2 V1/Z1)/Z2^2,
//   Z2 = N+1+M2/2+M3/6, q = (N+2+2M2+(4/3)M3)/Z2^2, out = A + k(qA - B).
// Dropped alpha^2 value-moments contribute <= ~1e-8 abs (Cauchy-Schwarz).
// ---------------------------------------------------------------------------
__global__ __launch_bounds__(256) void reduce_kernel(
    const float* __restrict__ p0, const float* __restrict__ p1,
    const float4* __restrict__ scal, float* __restrict__ out) {
  const int b = blockIdx.x;
  const int t = threadIdx.x;  // = f

  double V0 = 0.0, V1 = 0.0;
  const float* pb0 = p0 + (size_t)b * NCH * F_ + t;
  const float* pb1 = p1 + (size_t)b * NCH * F_ + t;
#pragma unroll 8
  for (int c = 0; c < NCH; ++c) {
    V0 += (double)pb0[(size_t)c * F_];
    V1 += (double)pb1[(size_t)c * F_];
  }

  __shared__ double sc[3];
  if (t < 64) {
    float4 s = scal[b * NCH + t];
    double z1 = (double)s.x, w2 = (double)s.y, w3 = (double)s.z;
#pragma unroll
    for (int off = 32; off > 0; off >>= 1) {
      z1 += __shfl_xor(z1, off, 64);
      w2 += __shfl_xor(w2, off, 64);
      w3 += __shfl_xor(w3, off, 64);
    }
    if (t == 0) { sc[0] = z1; sc[1] = w2; sc[2] = w3; }
  }
  __syncthreads();

  const double z1 = sc[0], w2 = sc[1], w3 = sc[2];
  const double iZ1 = 1.0 / z1;
  const double M2 = w2 * iZ1 * iZ1;
  const double M3 = w3 * iZ1 * iZ1 * iZ1;
  const double Z2 = (double)N_ + 1.0 + 0.5 * M2 + M3 / 6.0;
  const double T2 = (double)N_ + 2.0 + 2.0 * M2 + (4.0 / 3.0) * M3;
  const double iZ2 = 1.0 / Z2;
  const double qd = T2 * iZ2 * iZ2;

  const double W1 = V1 * iZ1;
  const double A  = (V0 + W1) * iZ2;
  const double Bd = (V0 + 2.0 * W1) * iZ2 * iZ2;
  const double C  = qd * A - Bd;

  float* ob = out + (size_t)b * K_ * F_ + t;
#pragma unroll
  for (int k = 0; k < K_; ++k) ob[(size_t)k * F_] = (float)(A + (double)k * C);
}

extern "C" void kernel_launch(void* const* d_in, const int* in_sizes, int n_in,
                              void* d_out, int out_size, void* d_ws, size_t ws_size,
                              hipStream_t stream) {
  const float* q = (const float*)d_in[0];
  const float* keys = (const float*)d_in[1];
  const float* values = (const float*)d_in[2];
  float* out = (float*)d_out;
  float* p0 = (float*)d_ws;                               // 8*64*256 floats = 512 KB
  float* p1 = p0 + (size_t)B_ * NCH * F_;                 // 512 KB
  float4* scal = (float4*)(p1 + (size_t)B_ * NCH * F_);   // 512 float4

  fused_kernel<<<dim3(B_ * NCH), dim3(512), 0, stream>>>(q, keys, values,
                                                         p0, p1, scal);
  reduce_kernel<<<dim3(B_), dim3(256), 0, stream>>>(p0, p1, scal, out);
}

// Round 6
// 120.324 us; speedup vs baseline: 1.0916x; 1.0503x over previous
//
#include <hip/hip_runtime.h>

#define B_ 8
#define D_ 256
#define N_ 32768
#define F_ 256
#define K_ 16
#define NCH 32        // chunks per batch
#define CHN 1024      // n per chunk

__device__ __forceinline__ float sum4(float4 v) { return v.x + v.y + v.z + v.w; }
__device__ __forceinline__ float dot4(float4 a, float4 b) {
  return a.x * b.x + a.y * b.y + a.z * b.z + a.w * b.w;
}

// ---------------------------------------------------------------------------
// Fused kernel: block = (b, chunk of 1024 n), 512 threads, 256 blocks (1/CU).
// Phase 1: e[chunk] -> LDS (2-way d-split) + exact scalars (Se, Se2, Se3).
// Phase 2: wave w owns f = w*32..+31 in 4 groups of 8. Per group: 16 register
//          accumulators (m0,m1 per f), 32 independent float4 loads, ONE
//          17-shfl merge-butterfly, 16 scalar stores. Peak live array = 16
//          floats (R4's 64-float array spilled at VGPR=48).
// ---------------------------------------------------------------------------
__global__ __launch_bounds__(512, 2) void fused_kernel(
    const float* __restrict__ q, const float* __restrict__ keys,
    const float* __restrict__ values, float* __restrict__ p0,
    float* __restrict__ p1, float4* __restrict__ scal) {
  const int b = blockIdx.x >> 5;
  const int ch = blockIdx.x & 31;
  const int t = threadIdx.x;
  const int c = t & 255;   // float4 n-column within chunk
  const int g = t >> 8;    // d-half (128 d each)

  __shared__ float qs[D_];
  __shared__ float4 part[256];
  __shared__ float e_lds[CHN];
  __shared__ float pr[8][3];

  if (t < D_) qs[t] = q[b * D_ + t];
  __syncthreads();

  // ---- Phase 1: keys -> e ----
  const int n0 = ch * CHN + c * 4;
  const float* kp = keys + (size_t)b * D_ * N_ + (size_t)(g * 128) * N_ + n0;
  const float* qg = qs + g * 128;
  float ax = 0.f, ay = 0.f, az = 0.f, aw = 0.f;
#pragma unroll 16
  for (int d = 0; d < 128; ++d) {
    float4 kv = *reinterpret_cast<const float4*>(kp + (size_t)d * N_);
    float qd = qg[d];
    ax += qd * kv.x; ay += qd * kv.y; az += qd * kv.z; aw += qd * kv.w;
  }
  if (g) part[c] = make_float4(ax, ay, az, aw);
  __syncthreads();

  float s1 = 0.f, s2 = 0.f, s3 = 0.f;
  if (!g) {
    float4 p = part[c];
    float4 ev;
    ev.x = __expf(-0.0625f * (ax + p.x));
    ev.y = __expf(-0.0625f * (ay + p.y));
    ev.z = __expf(-0.0625f * (az + p.z));
    ev.w = __expf(-0.0625f * (aw + p.w));
    *reinterpret_cast<float4*>(e_lds + c * 4) = ev;
    float4 e2 = make_float4(ev.x * ev.x, ev.y * ev.y, ev.z * ev.z, ev.w * ev.w);
    s1 = sum4(ev);
    s2 = sum4(e2);
    s3 = e2.x * ev.x + e2.y * ev.y + e2.z * ev.z + e2.w * ev.w;
  }
#pragma unroll
  for (int off = 32; off > 0; off >>= 1) {
    s1 += __shfl_xor(s1, off, 64);
    s2 += __shfl_xor(s2, off, 64);
    s3 += __shfl_xor(s3, off, 64);
  }
  if ((t & 63) == 0) { pr[t >> 6][0] = s1; pr[t >> 6][1] = s2; pr[t >> 6][2] = s3; }
  __syncthreads();   // also publishes e_lds to all waves
  if (t == 0) {
    float r1 = 0.f, r2 = 0.f, r3 = 0.f;
#pragma unroll
    for (int w = 0; w < 8; ++w) { r1 += pr[w][0]; r2 += pr[w][1]; r3 += pr[w][2]; }
    scal[b * NCH + ch] = make_float4(r1, r2, r3, 0.f);
  }

  // ---- Phase 2: values sweep ----
  const int w = t >> 6, lane = t & 63;
  float4 e4[4];
#pragma unroll
  for (int it = 0; it < 4; ++it)
    e4[it] = *reinterpret_cast<const float4*>(e_lds + it * 256 + lane * 4);

  const size_t nb = (size_t)ch * CHN + lane * 4;
  const size_t prow = (size_t)(b * NCH + ch) * F_;

#pragma unroll
  for (int grp = 0; grp < 4; ++grp) {
    const int f0 = w * 32 + grp * 8;
    const float* vb = values + ((size_t)b * F_ + f0) * N_ + nb;

    float vals[16];
#pragma unroll
    for (int i = 0; i < 16; ++i) vals[i] = 0.f;

#pragma unroll
    for (int j = 0; j < 8; ++j) {
      const float* vr = vb + (size_t)j * N_;
#pragma unroll
      for (int it = 0; it < 4; ++it) {
        float4 v4 = *reinterpret_cast<const float4*>(vr + it * 256);
        vals[j]     += sum4(v4);
        vals[8 + j] += dot4(v4, e4[it]);
      }
    }

    // merge-butterfly: 16 vals -> lane L holds total of index (L & 15)
#pragma unroll
    for (int lev = 0; lev < 4; ++lev) {
      const int s = 8 >> lev;
      const int nv = 8 >> lev;
      const bool upper = (lane & s) != 0;
#pragma unroll
      for (int i = 0; i < nv; ++i) {
        float keep = upper ? vals[i + nv] : vals[i];
        float send = upper ? vals[i] : vals[i + nv];
        vals[i] = keep + __shfl_xor(send, s, 64);
      }
    }
    vals[0] += __shfl_xor(vals[0], 16, 64);
    vals[0] += __shfl_xor(vals[0], 32, 64);

    if (lane < 8)            p0[prow + f0 + lane] = vals[0];
    else if (lane < 16)      p1[prow + f0 + lane - 8] = vals[0];
  }
}

// ---------------------------------------------------------------------------
// Reduce kernel: 8 blocks x 256 threads; thread = f. Sum 32 chunk partials in
// double, then analytic epilogue:
//   A = (V0 + V1/Z1)/Z2, B = (V0 + 2 V1/Z1)/Z2^2,
//   Z2 = N+1+M2/2+M3/6, q = (N+2+2M2+(4/3)M3)/Z2^2, out = A + k(qA - B).
// (validated in R3/R4; dropped alpha^2 value-moments <= ~1e-8 abs)
// ---------------------------------------------------------------------------
__global__ __launch_bounds__(256) void reduce_kernel(
    const float* __restrict__ p0, const float* __restrict__ p1,
    const float4* __restrict__ scal, float* __restrict__ out) {
  const int b = blockIdx.x;
  const int t = threadIdx.x;  // = f

  double V0 = 0.0, V1 = 0.0;
  const float* pb0 = p0 + (size_t)b * NCH * F_ + t;
  const float* pb1 = p1 + (size_t)b * NCH * F_ + t;
#pragma unroll 8
  for (int c = 0; c < NCH; ++c) {
    V0 += (double)pb0[(size_t)c * F_];
    V1 += (double)pb1[(size_t)c * F_];
  }

  __shared__ double sc[3];
  if (t < 64) {
    float4 s = (t < NCH) ? scal[b * NCH + t] : make_float4(0.f, 0.f, 0.f, 0.f);
    double z1 = (double)s.x, w2 = (double)s.y, w3 = (double)s.z;
#pragma unroll
    for (int off = 32; off > 0; off >>= 1) {
      z1 += __shfl_xor(z1, off, 64);
      w2 += __shfl_xor(w2, off, 64);
      w3 += __shfl_xor(w3, off, 64);
    }
    if (t == 0) { sc[0] = z1; sc[1] = w2; sc[2] = w3; }
  }
  __syncthreads();

  const double z1 = sc[0], w2 = sc[1], w3 = sc[2];
  const double iZ1 = 1.0 / z1;
  const double M2 = w2 * iZ1 * iZ1;
  const double M3 = w3 * iZ1 * iZ1 * iZ1;
  const double Z2 = (double)N_ + 1.0 + 0.5 * M2 + M3 / 6.0;
  const double T2 = (double)N_ + 2.0 + 2.0 * M2 + (4.0 / 3.0) * M3;
  const double iZ2 = 1.0 / Z2;
  const double qd = T2 * iZ2 * iZ2;

  const double W1 = V1 * iZ1;
  const double A  = (V0 + W1) * iZ2;
  const double Bd = (V0 + 2.0 * W1) * iZ2 * iZ2;
  const double C  = qd * A - Bd;

  float* ob = out + (size_t)b * K_ * F_ + t;
#pragma unroll
  for (int k = 0; k < K_; ++k) ob[(size_t)k * F_] = (float)(A + (double)k * C);
}

extern "C" void kernel_launch(void* const* d_in, const int* in_sizes, int n_in,
                              void* d_out, int out_size, void* d_ws, size_t ws_size,
                              hipStream_t stream) {
  const float* q = (const float*)d_in[0];
  const float* keys = (const float*)d_in[1];
  const float* values = (const float*)d_in[2];
  float* out = (float*)d_out;
  float* p0 = (float*)d_ws;                               // 8*32*256 floats = 256 KB
  float* p1 = p0 + (size_t)B_ * NCH * F_;                 // 256 KB
  float4* scal = (float4*)(p1 + (size_t)B_ * NCH * F_);   // 256 float4

  fused_kernel<<<dim3(B_ * NCH), dim3(512), 0, stream>>>(q, keys, values,
                                                         p0, p1, scal);
  reduce_kernel<<<dim3(B_), dim3(256), 0, stream>>>(p0, p1, scal, out);
}